// Round 2
// baseline (504.630 us; speedup 1.0000x reference)
//
#include <hip/hip_runtime.h>
#include <hip/hip_bf16.h>

// Problem constants (B=1)
#define S_LEN 2048
#define HDIM  1024
#define NHEAD 16
#define DHEAD 64
#define SCALE_F 0.125f   // 1/sqrt(64)

typedef __bf16 bf16;
typedef __bf16 bf16x4 __attribute__((ext_vector_type(4)));
typedef __bf16 bf16x8 __attribute__((ext_vector_type(8)));
typedef float  f32x4  __attribute__((ext_vector_type(4)));

#define MFMA16(a,b,c) __builtin_amdgcn_mfma_f32_16x16x32_bf16((a),(b),(c),0,0,0)

// ---------------- fp32 -> bf16 convert (vectorized) ----------------
__global__ void cvt_f32_bf16_kernel(const float* __restrict__ in,
                                    bf16* __restrict__ out, int n4) {
  int i = blockIdx.x * blockDim.x + threadIdx.x;
  int stride = gridDim.x * blockDim.x;
  for (; i < n4; i += stride) {
    float4 v = ((const float4*)in)[i];
    bf16x4 o = { (bf16)v.x, (bf16)v.y, (bf16)v.z, (bf16)v.w };
    ((bf16x4*)out)[i] = o;
  }
}

// ---------------- transpose + convert: W[rows][cols] f32 -> Wt[cols][rows] bf16
struct TrJob { const float* in; bf16* out; };
struct TrArgs { TrJob j[8]; };

__global__ void transp_cvt_kernel(TrArgs args, int rows, int cols) {
  TrJob t = args.j[blockIdx.z];
  __shared__ float tile[32][33];
  int tx = threadIdx.x, ty = threadIdx.y;
  int c0 = blockIdx.x * 32, r0 = blockIdx.y * 32;
  for (int j = ty; j < 32; j += 8)
    tile[j][tx] = t.in[(size_t)(r0 + j) * cols + c0 + tx];
  __syncthreads();
  for (int j = ty; j < 32; j += 8)
    t.out[(size_t)(c0 + j) * rows + r0 + tx] = (bf16)tile[tx][j];
}

// ---------------- per-head transpose: in[S][H] bf16 -> out[NH][DHEAD][S] bf16
__global__ void transp_head_kernel(const bf16* __restrict__ in,
                                   bf16* __restrict__ out) {
  __shared__ bf16 tile[32][33];
  int h = blockIdx.z;
  int t0 = blockIdx.x * 32, d0 = blockIdx.y * 32;
  int tx = threadIdx.x, ty = threadIdx.y;
  for (int j = ty; j < 32; j += 8)
    tile[j][tx] = in[(size_t)(t0 + j) * HDIM + h * DHEAD + d0 + tx];
  __syncthreads();
  for (int j = ty; j < 32; j += 8)
    out[((size_t)h * DHEAD + d0 + j) * S_LEN + t0 + tx] = tile[tx][j];
}

// ---------------- batched bf16 GEMM: C[M][N] = A[M][K] * Bt[N][K]^T + bias ---
// 128x128 tile, 4 waves (2x2), each wave 64x64 via 4x4 16x16x32 MFMA frags.
struct GemmJob { const bf16* A; const bf16* Bt; const float* bias; bf16* Cb; float* Cf; };
struct GemmArgs { GemmJob j[6]; };

__launch_bounds__(256)
__global__ void gemm_bt_kernel(GemmArgs args, int M, int N, int K) {
  GemmJob jb = args.j[blockIdx.z];
  const int bn = blockIdx.x, bm = blockIdx.y;
  const int tid = threadIdx.x;
  const int wave = tid >> 6, lane = tid & 63;
  const int wr = wave >> 1, wc = wave & 1;
  const int l16 = lane & 15, lq = lane >> 4;

  __shared__ alignas(16) bf16 As[128][40];  // pad: row stride 80B (16B mult)
  __shared__ alignas(16) bf16 Bs[128][40];

  f32x4 acc[4][4];
#pragma unroll
  for (int i = 0; i < 4; ++i)
#pragma unroll
    for (int j = 0; j < 4; ++j) acc[i][j] = (f32x4){0.f, 0.f, 0.f, 0.f};

  const bf16* Ap = jb.A + (size_t)bm * 128 * K;
  const bf16* Bp = jb.Bt + (size_t)bn * 128 * K;

  for (int kt = 0; kt < K; kt += 32) {
    __syncthreads();
#pragma unroll
    for (int it = 0; it < 2; ++it) {
      int idx = tid + it * 256;            // 512 chunks of 8 bf16 per matrix
      int r = idx >> 2, c8 = (idx & 3) << 3;
      *(bf16x8*)(&As[r][c8]) = *(const bf16x8*)(Ap + (size_t)r * K + kt + c8);
      *(bf16x8*)(&Bs[r][c8]) = *(const bf16x8*)(Bp + (size_t)r * K + kt + c8);
    }
    __syncthreads();

    bf16x8 af[4], bfr[4];
#pragma unroll
    for (int i = 0; i < 4; ++i)
      af[i] = *(const bf16x8*)(&As[wr * 64 + i * 16 + l16][lq * 8]);
#pragma unroll
    for (int j = 0; j < 4; ++j)
      bfr[j] = *(const bf16x8*)(&Bs[wc * 64 + j * 16 + l16][lq * 8]);
#pragma unroll
    for (int i = 0; i < 4; ++i)
#pragma unroll
      for (int j = 0; j < 4; ++j)
        acc[i][j] = MFMA16(af[i], bfr[j], acc[i][j]);
  }

  // epilogue: C row = (lq*4 + r), col = l16  (m89-verified C/D layout)
#pragma unroll
  for (int i = 0; i < 4; ++i) {
#pragma unroll
    for (int j = 0; j < 4; ++j) {
      int row0 = bm * 128 + wr * 64 + i * 16 + lq * 4;
      int col  = bn * 128 + wc * 64 + j * 16 + l16;
      float bv = jb.bias ? jb.bias[col] : 0.0f;
#pragma unroll
      for (int r = 0; r < 4; ++r) {
        float v = acc[i][j][r] + bv;
        size_t off = (size_t)(row0 + r) * N + col;
        if (jb.Cb) jb.Cb[off] = (bf16)v;
        if (jb.Cf) jb.Cf[off] = v;
      }
    }
  }
}

// ---------------- flash attention (non-causal), 64 q-rows/block -------------
// Q [S][H] bf16 (head slice), K [S][H] bf16, VT [NH][DHEAD][S] bf16.
// grid: (S/64, NH, P). Online softmax; P via per-wave LDS round-trip.
__launch_bounds__(256)
__global__ void flash_attn_kernel(const bf16* __restrict__ Q,
                                  const bf16* __restrict__ Kin,
                                  const bf16* __restrict__ VT,
                                  bf16* __restrict__ Ob,
                                  float* __restrict__ Of,
                                  size_t kStride, size_t vStride, size_t oStride) {
  const int qb = blockIdx.x, h = blockIdx.y, p = blockIdx.z;
  const bf16* Kp = Kin + (size_t)p * kStride;
  const bf16* Vp = VT + (size_t)p * vStride;
  const int tid = threadIdx.x;
  const int wave = tid >> 6, lane = tid & 63;
  const int l16 = lane & 15, lq = lane >> 4;

  __shared__ alignas(16) bf16 Ks[64][72];
  __shared__ alignas(16) bf16 Vs[64][72];
  __shared__ alignas(16) bf16 Ps[4][16][72];

  // Q A-fragments (D=64 -> 2 k-steps of 32)
  bf16x8 qf[2];
  {
    const bf16* qptr = Q + (size_t)(qb * 64 + wave * 16 + l16) * HDIM + h * DHEAD + lq * 8;
    qf[0] = *(const bf16x8*)qptr;
    qf[1] = *(const bf16x8*)(qptr + 32);
  }

  float m_run[4], l_run[4];
  f32x4 oacc[4];
#pragma unroll
  for (int r = 0; r < 4; ++r) { m_run[r] = -1e30f; l_run[r] = 0.f; }
#pragma unroll
  for (int j = 0; j < 4; ++j) oacc[j] = (f32x4){0.f, 0.f, 0.f, 0.f};

  for (int tb = 0; tb < S_LEN / 64; ++tb) {
    __syncthreads();
#pragma unroll
    for (int it = 0; it < 2; ++it) {
      int idx = tid + it * 256;          // 512 chunks of 8 bf16 per tile
      int r = idx >> 3, c8 = (idx & 7) << 3;
      *(bf16x8*)(&Ks[r][c8]) = *(const bf16x8*)(Kp + (size_t)(tb * 64 + r) * HDIM + h * DHEAD + c8);
      *(bf16x8*)(&Vs[r][c8]) = *(const bf16x8*)(Vp + ((size_t)h * DHEAD + r) * S_LEN + tb * 64 + c8);
    }
    __syncthreads();

    // S = Q K^T * SCALE : 4 col-frags x 2 k-steps
    f32x4 sf[4];
#pragma unroll
    for (int j = 0; j < 4; ++j) sf[j] = (f32x4){0.f, 0.f, 0.f, 0.f};
#pragma unroll
    for (int j = 0; j < 4; ++j)
#pragma unroll
      for (int kk = 0; kk < 2; ++kk) {
        bf16x8 kf = *(const bf16x8*)(&Ks[j * 16 + l16][kk * 32 + lq * 8]);
        sf[j] = MFMA16(qf[kk], kf, sf[j]);
      }

    // online softmax over this 64-wide block
    float mx[4];
#pragma unroll
    for (int r = 0; r < 4; ++r) {
      sf[0][r] *= SCALE_F; sf[1][r] *= SCALE_F; sf[2][r] *= SCALE_F; sf[3][r] *= SCALE_F;
      mx[r] = fmaxf(fmaxf(sf[0][r], sf[1][r]), fmaxf(sf[2][r], sf[3][r]));
    }
#pragma unroll
    for (int m = 1; m < 16; m <<= 1)
#pragma unroll
      for (int r = 0; r < 4; ++r) mx[r] = fmaxf(mx[r], __shfl_xor(mx[r], m, 16));

    float corr[4], rs[4];
#pragma unroll
    for (int r = 0; r < 4; ++r) {
      float mnew = fmaxf(m_run[r], mx[r]);
      corr[r] = __expf(m_run[r] - mnew);
      m_run[r] = mnew;
      rs[r] = 0.f;
    }
#pragma unroll
    for (int j = 0; j < 4; ++j)
#pragma unroll
      for (int r = 0; r < 4; ++r) {
        float pv = __expf(sf[j][r] - m_run[r]);
        sf[j][r] = pv;
        rs[r] += pv;
      }
#pragma unroll
    for (int m = 1; m < 16; m <<= 1)
#pragma unroll
      for (int r = 0; r < 4; ++r) rs[r] += __shfl_xor(rs[r], m, 16);
#pragma unroll
    for (int r = 0; r < 4; ++r) l_run[r] = l_run[r] * corr[r] + rs[r];
#pragma unroll
    for (int j = 0; j < 4; ++j)
#pragma unroll
      for (int r = 0; r < 4; ++r) oacc[j][r] *= corr[r];

    // P -> LDS (bf16), then PV MFMA
#pragma unroll
    for (int j = 0; j < 4; ++j)
#pragma unroll
      for (int r = 0; r < 4; ++r)
        Ps[wave][lq * 4 + r][j * 16 + l16] = (bf16)sf[j][r];
    __syncthreads();

    bf16x8 pf[2];
    pf[0] = *(const bf16x8*)(&Ps[wave][l16][lq * 8]);
    pf[1] = *(const bf16x8*)(&Ps[wave][l16][32 + lq * 8]);
#pragma unroll
    for (int j = 0; j < 4; ++j)
#pragma unroll
      for (int kk = 0; kk < 2; ++kk) {
        bf16x8 vf = *(const bf16x8*)(&Vs[j * 16 + l16][kk * 32 + lq * 8]);
        oacc[j] = MFMA16(pf[kk], vf, oacc[j]);
      }
  }

  float* Ofp = Of ? Of + (size_t)p * oStride : nullptr;
#pragma unroll
  for (int r = 0; r < 4; ++r) {
    float inv = 1.0f / l_run[r];
    int row = qb * 64 + wave * 16 + lq * 4 + r;
#pragma unroll
    for (int j = 0; j < 4; ++j) {
      float v = oacc[j][r] * inv;
      size_t off = (size_t)row * HDIM + h * DHEAD + j * 16 + l16;
      if (Ob)  Ob[off] = (bf16)v;
      if (Ofp) Ofp[off] = v;
    }
  }
}

// ---------------- mean over P + build concat matrix -------------------------
__global__ void mean_gate_prep_kernel(const float* __restrict__ rc,   // [2][S][H]
                                      const bf16* __restrict__ outb,  // [S][H]
                                      float* __restrict__ rof,        // [S][H]
                                      bf16* __restrict__ acat,        // [S][2H]
                                      int n) {
  int i = blockIdx.x * blockDim.x + threadIdx.x;
  int stride = gridDim.x * blockDim.x;
  for (; i < n; i += stride) {
    float ro = 0.5f * (rc[i] + rc[i + n]);
    rof[i] = ro;
    int srow = i >> 10, col = i & 1023;
    size_t base = (size_t)srow * 2048;
    acat[base + col] = outb[i];
    acat[base + 1024 + col] = (bf16)ro;
  }
}

// ---------------- final gating ----------------------------------------------
__global__ void final_gate_kernel(const float* __restrict__ outf,
                                  const float* __restrict__ rof,
                                  const float* __restrict__ glog,
                                  float* __restrict__ out, int n) {
  int i = blockIdx.x * blockDim.x + threadIdx.x;
  int stride = gridDim.x * blockDim.x;
  for (; i < n; i += stride) {
    float g = 1.0f / (1.0f + __expf(-glog[i]));
    out[i] = outf[i] * (1.0f - g) + rof[i] * g;
  }
}

// ============================================================================
extern "C" void kernel_launch(void* const* d_in, const int* in_sizes, int n_in,
                              void* d_out, int out_size, void* d_ws, size_t ws_size,
                              hipStream_t stream) {
  const float* hs   = (const float*)d_in[0];
  const float* past = (const float*)d_in[1];
  const float* Wq = (const float*)d_in[2];   const float* bq = (const float*)d_in[3];
  const float* Wk = (const float*)d_in[4];   const float* bk = (const float*)d_in[5];
  const float* Wv = (const float*)d_in[6];   const float* bv = (const float*)d_in[7];
  const float* Wo = (const float*)d_in[8];   const float* bo = (const float*)d_in[9];
  const float* Wrq = (const float*)d_in[10]; const float* brq = (const float*)d_in[11];
  const float* Wrk = (const float*)d_in[12]; const float* brk = (const float*)d_in[13];
  const float* Wrv = (const float*)d_in[14]; const float* brv = (const float*)d_in[15];
  const float* Wg  = (const float*)d_in[16]; const float* bg  = (const float*)d_in[17];

  char* wp = (char*)d_ws;
  auto alloc = [&](size_t bytes) -> void* {
    void* p = (void*)wp;
    wp += (bytes + 255) & ~(size_t)255;
    return p;
  };
  const size_t NE = (size_t)S_LEN * HDIM;  // 2M elements

  bf16* hs_b   = (bf16*)alloc(NE * 2);
  bf16* past_b = (bf16*)alloc(2 * NE * 2);
  bf16* Wqt  = (bf16*)alloc((size_t)HDIM * HDIM * 2);
  bf16* Wkt  = (bf16*)alloc((size_t)HDIM * HDIM * 2);
  bf16* Wvt  = (bf16*)alloc((size_t)HDIM * HDIM * 2);
  bf16* Wot  = (bf16*)alloc((size_t)HDIM * HDIM * 2);
  bf16* Wrqt = (bf16*)alloc((size_t)HDIM * HDIM * 2);
  bf16* Wrkt = (bf16*)alloc((size_t)HDIM * HDIM * 2);
  bf16* Wrvt = (bf16*)alloc((size_t)HDIM * HDIM * 2);
  bf16* Wgt  = (bf16*)alloc((size_t)2 * HDIM * HDIM * 2);  // [1024][2048]
  bf16* q_b   = (bf16*)alloc(NE * 2);
  bf16* k_b   = (bf16*)alloc(NE * 2);
  bf16* v_b   = (bf16*)alloc(NE * 2);
  bf16* vT_b  = (bf16*)alloc(NE * 2);
  bf16* ctx_b = (bf16*)alloc(NE * 2);
  bf16* out_b = (bf16*)alloc(NE * 2);
  float* out_f = (float*)alloc(NE * 4);
  bf16* rq_b  = (bf16*)alloc(NE * 2);
  bf16* rk_b  = (bf16*)alloc(2 * NE * 2);
  bf16* rv_b  = (bf16*)alloc(2 * NE * 2);
  bf16* rvT_b = (bf16*)alloc(2 * NE * 2);
  float* rctx_f = (float*)alloc(2 * NE * 4);
  float* ro_f   = (float*)alloc(NE * 4);
  bf16* acat_b  = (bf16*)alloc(2 * NE * 2);
  float* glog_f = (float*)alloc(NE * 4);

  // 1. convert activations to bf16
  cvt_f32_bf16_kernel<<<2048, 256, 0, stream>>>(hs, hs_b, (int)(NE / 4));
  cvt_f32_bf16_kernel<<<2048, 256, 0, stream>>>(past, past_b, (int)(2 * NE / 4));

  // 2. transpose+convert weights (Bt layout [N][K])
  TrArgs ta{};
  ta.j[0] = {Wq, Wqt};  ta.j[1] = {Wk, Wkt};  ta.j[2] = {Wv, Wvt};
  ta.j[3] = {Wo, Wot};  ta.j[4] = {Wrq, Wrqt}; ta.j[5] = {Wrk, Wrkt};
  ta.j[6] = {Wrv, Wrvt};
  transp_cvt_kernel<<<dim3(32, 32, 7), dim3(32, 8), 0, stream>>>(ta, 1024, 1024);
  TrArgs tg{};
  tg.j[0] = {Wg, Wgt};
  transp_cvt_kernel<<<dim3(32, 64, 1), dim3(32, 8), 0, stream>>>(tg, 2048, 1024);

  // 3. q,k,v (batched over z)
  GemmArgs g1{};
  g1.j[0] = {hs_b, Wqt, bq, q_b, nullptr};
  g1.j[1] = {hs_b, Wkt, bk, k_b, nullptr};
  g1.j[2] = {hs_b, Wvt, bv, v_b, nullptr};
  gemm_bt_kernel<<<dim3(8, 16, 3), 256, 0, stream>>>(g1, 2048, 1024, 1024);

  // 4. per-head V transpose
  transp_head_kernel<<<dim3(64, 2, 16), dim3(32, 8), 0, stream>>>(v_b, vT_b);

  // 5. self-attention
  flash_attn_kernel<<<dim3(32, 16, 1), 256, 0, stream>>>(
      q_b, k_b, vT_b, ctx_b, nullptr, 0, 0, 0);

  // 6. output projection (bf16 + fp32 outputs)
  GemmArgs g2{};
  g2.j[0] = {ctx_b, Wot, bo, out_b, out_f};
  gemm_bt_kernel<<<dim3(8, 16, 1), 256, 0, stream>>>(g2, 2048, 1024, 1024);

  // 7. rq, rk(p), rv(p)
  GemmArgs g3{};
  g3.j[0] = {out_b,        Wrqt, brq, rq_b,        nullptr};
  g3.j[1] = {past_b,       Wrkt, brk, rk_b,        nullptr};
  g3.j[2] = {past_b + NE,  Wrkt, brk, rk_b + NE,   nullptr};
  g3.j[3] = {past_b,       Wrvt, brv, rv_b,        nullptr};
  g3.j[4] = {past_b + NE,  Wrvt, brv, rv_b + NE,   nullptr};
  gemm_bt_kernel<<<dim3(8, 16, 5), 256, 0, stream>>>(g3, 2048, 1024, 1024);

  // 8. per-head rv transposes
  transp_head_kernel<<<dim3(64, 2, 16), dim3(32, 8), 0, stream>>>(rv_b, rvT_b);
  transp_head_kernel<<<dim3(64, 2, 16), dim3(32, 8), 0, stream>>>(rv_b + NE, rvT_b + NE);

  // 9. recursive attention (z = p)
  flash_attn_kernel<<<dim3(32, 16, 2), 256, 0, stream>>>(
      rq_b, rk_b, rvT_b, nullptr, rctx_f, NE, NE, NE);

  // 10. mean over P + concat matrix
  mean_gate_prep_kernel<<<2048, 256, 0, stream>>>(rctx_f, out_b, ro_f, acat_b, (int)NE);

  // 11. gate logits: [S][2H] @ Wg
  GemmArgs g4{};
  g4.j[0] = {acat_b, Wgt, bg, nullptr, glog_f};
  gemm_bt_kernel<<<dim3(8, 16, 1), 256, 0, stream>>>(g4, 2048, 1024, 2048);

  // 12. final gated combine -> d_out (fp32)
  final_gate_kernel<<<2048, 256, 0, stream>>>(out_f, ro_f, glog_f, (float*)d_out, (int)NE);
}

// Round 3
// 474.554 us; speedup vs baseline: 1.0634x; 1.0634x over previous
//
#include <hip/hip_runtime.h>
#include <hip/hip_bf16.h>

// Problem constants (B=1)
#define S_LEN 2048
#define HDIM  1024
#define NHEAD 16
#define DHEAD 64
#define SCALE_F 0.125f                 // 1/sqrt(64)
#define QSCALE  (0.125f * 1.44269504088896340736f)  // SCALE * log2(e), folded into Q

typedef __bf16 bf16;
typedef __bf16 bf16x4 __attribute__((ext_vector_type(4)));
typedef __bf16 bf16x8 __attribute__((ext_vector_type(8)));
typedef float  f32x4  __attribute__((ext_vector_type(4)));

#define MFMA16(a,b,c) __builtin_amdgcn_mfma_f32_16x16x32_bf16((a),(b),(c),0,0,0)

// async global->LDS, 16B per lane; dest is wave-uniform base + lane*16 (m104)
__device__ __forceinline__ void gload16(const bf16* g, bf16* lds_wave_base) {
  __builtin_amdgcn_global_load_lds(
      (const __attribute__((address_space(1))) void*)g,
      (__attribute__((address_space(3))) void*)lds_wave_base, 16, 0, 0);
}

// ---------------- fp32 -> bf16 convert (vectorized) ----------------
__global__ void cvt_f32_bf16_kernel(const float* __restrict__ in,
                                    bf16* __restrict__ out, int n4) {
  int i = blockIdx.x * blockDim.x + threadIdx.x;
  int stride = gridDim.x * blockDim.x;
  for (; i < n4; i += stride) {
    float4 v = ((const float4*)in)[i];
    bf16x4 o = { (bf16)v.x, (bf16)v.y, (bf16)v.z, (bf16)v.w };
    ((bf16x4*)out)[i] = o;
  }
}

// ---------------- transpose + convert: W[rows][cols] f32 -> Wt[cols][rows] bf16
struct TrJob { const float* in; bf16* out; };
struct TrArgs { TrJob j[8]; };

__global__ void transp_cvt_kernel(TrArgs args, int rows, int cols) {
  TrJob t = args.j[blockIdx.z];
  __shared__ float tile[32][33];
  int tx = threadIdx.x, ty = threadIdx.y;
  int c0 = blockIdx.x * 32, r0 = blockIdx.y * 32;
  for (int j = ty; j < 32; j += 8)
    tile[j][tx] = t.in[(size_t)(r0 + j) * cols + c0 + tx];
  __syncthreads();
  for (int j = ty; j < 32; j += 8)
    t.out[(size_t)(c0 + j) * rows + r0 + tx] = (bf16)tile[tx][j];
}

// ---------------- per-head transpose: in[S][H] bf16 -> out[NH][DHEAD][S] bf16
__global__ void transp_head_kernel(const bf16* __restrict__ in,
                                   bf16* __restrict__ out) {
  __shared__ bf16 tile[32][33];
  int h = blockIdx.z;
  int t0 = blockIdx.x * 32, d0 = blockIdx.y * 32;
  int tx = threadIdx.x, ty = threadIdx.y;
  for (int j = ty; j < 32; j += 8)
    tile[j][tx] = in[(size_t)(t0 + j) * HDIM + h * DHEAD + d0 + tx];
  __syncthreads();
  for (int j = ty; j < 32; j += 8)
    out[((size_t)h * DHEAD + d0 + j) * S_LEN + t0 + tx] = tile[tx][j];
}

// ---------------- batched bf16 GEMM: C[M][N] = (A[M][K] * Bt[N][K]^T + bias)*cscale
// 128x128 tile, 4 waves (2x2), 4x4 16x16x32 MFMA frags, global_load_lds staging (m97)
struct GemmJob { const bf16* A; const bf16* Bt; const float* bias; bf16* Cb; float* Cf; float cscale; };
struct GemmArgs { GemmJob j[6]; };

__launch_bounds__(256)
__global__ void gemm_bt_kernel(GemmArgs args, int M, int N, int K) {
  GemmJob jb = args.j[blockIdx.z];
  const int bn = blockIdx.x, bm = blockIdx.y;
  const int tid = threadIdx.x;
  const int wave = tid >> 6, lane = tid & 63;
  const int wr = wave >> 1, wc = wave & 1;
  const int l16 = lane & 15, lq = lane >> 4;

  __shared__ alignas(16) bf16 As[128 * 32];  // LINEAR (global_load_lds requirement)
  __shared__ alignas(16) bf16 Bs[128 * 32];

  f32x4 acc[4][4];
#pragma unroll
  for (int i = 0; i < 4; ++i)
#pragma unroll
    for (int j = 0; j < 4; ++j) acc[i][j] = (f32x4){0.f, 0.f, 0.f, 0.f};

  const bf16* Ap = jb.A + (size_t)bm * 128 * K;
  const bf16* Bp = jb.Bt + (size_t)bn * 128 * K;

  // staging map: idx8 = issue*256 + tid -> row = idx8>>2, col8 = (idx8&3)*8
  const int r0 = tid >> 2,           c0 = (tid & 3) << 3;
  const int r1 = (tid + 256) >> 2,   c1 = ((tid + 256) & 3) << 3;
  bf16* ldsA0 = As + wave * 512;          // issue0 wave base (bytes: wave*1024)
  bf16* ldsA1 = As + 2048 + wave * 512;   // issue1 base (4096B + wave*1024)
  bf16* ldsB0 = Bs + wave * 512;
  bf16* ldsB1 = Bs + 2048 + wave * 512;

  for (int kt = 0; kt < K; kt += 32) {
    __syncthreads();
    gload16(Ap + (size_t)r0 * K + kt + c0, ldsA0);
    gload16(Ap + (size_t)r1 * K + kt + c1, ldsA1);
    gload16(Bp + (size_t)r0 * K + kt + c0, ldsB0);
    gload16(Bp + (size_t)r1 * K + kt + c1, ldsB1);
    __syncthreads();   // compiler emits vmcnt(0) drain before barrier

    bf16x8 af[4], bfr[4];
#pragma unroll
    for (int i = 0; i < 4; ++i)
      af[i] = *(const bf16x8*)(As + (size_t)(wr * 64 + i * 16 + l16) * 32 + lq * 8);
#pragma unroll
    for (int j = 0; j < 4; ++j)
      bfr[j] = *(const bf16x8*)(Bs + (size_t)(wc * 64 + j * 16 + l16) * 32 + lq * 8);
#pragma unroll
    for (int i = 0; i < 4; ++i)
#pragma unroll
      for (int j = 0; j < 4; ++j)
        acc[i][j] = MFMA16(af[i], bfr[j], acc[i][j]);
  }

  // epilogue: C row = lq*4+r, col = l16 (m89-verified)
#pragma unroll
  for (int i = 0; i < 4; ++i) {
#pragma unroll
    for (int j = 0; j < 4; ++j) {
      int row0 = bm * 128 + wr * 64 + i * 16 + lq * 4;
      int col  = bn * 128 + wc * 64 + j * 16 + l16;
      float bv = jb.bias ? jb.bias[col] : 0.0f;
#pragma unroll
      for (int r = 0; r < 4; ++r) {
        float v = (acc[i][j][r] + bv) * jb.cscale;
        size_t off = (size_t)(row0 + r) * N + col;
        if (jb.Cb) jb.Cb[off] = (bf16)v;
        if (jb.Cf) jb.Cf[off] = v;
      }
    }
  }
}

// ---------------- flash attention, swapped-QK^T (S^T layout) -----------------
// Q [S][H] bf16 PRE-SCALED by QSCALE; K [S][H]; VT [NH][DHEAD][S].
// grid: (S/64, NH, P). Each lane owns one q-row (q = l16): softmax in-register,
// P round-trip per-wave (no barrier), PV computes O^T = VT * P.
__launch_bounds__(256)
__global__ void flash_attn_kernel(const bf16* __restrict__ Q,
                                  const bf16* __restrict__ Kin,
                                  const bf16* __restrict__ VT,
                                  bf16* __restrict__ Ob,
                                  float* __restrict__ Of,
                                  size_t kStride, size_t vStride, size_t oStride) {
  const int qb = blockIdx.x, h = blockIdx.y, p = blockIdx.z;
  const bf16* Kp = Kin + (size_t)p * kStride;
  const bf16* Vp = VT + (size_t)p * vStride;
  const int tid = threadIdx.x;
  const int wave = tid >> 6, lane = tid & 63;
  const int l16 = lane & 15, lq = lane >> 4;

  __shared__ alignas(16) bf16 Ks[64][72];       // [t][d]
  __shared__ alignas(16) bf16 Vs[64][72];       // [d][t]
  __shared__ alignas(16) bf16 Ps[4][16][72];    // per-wave [q][t]

  // Q as B-frag: lane holds Q[q = wave*16+l16][d = kk*32 + lq*8 ..+7]
  bf16x8 qf[2];
  {
    const bf16* qptr = Q + (size_t)(qb * 64 + wave * 16 + l16) * HDIM + h * DHEAD + lq * 8;
    qf[0] = *(const bf16x8*)qptr;
    qf[1] = *(const bf16x8*)(qptr + 32);
  }

  float m_run = -1e30f, l_run = 0.f;
  f32x4 oacc[4];                                // O^T: d = j*16+lq*4+r, q = l16
#pragma unroll
  for (int j = 0; j < 4; ++j) oacc[j] = (f32x4){0.f, 0.f, 0.f, 0.f};

  for (int tb = 0; tb < S_LEN / 64; ++tb) {
    __syncthreads();
#pragma unroll
    for (int it = 0; it < 2; ++it) {
      int idx = tid + it * 256;
      int r = idx >> 3, c8 = (idx & 7) << 3;
      *(bf16x8*)(&Ks[r][c8]) = *(const bf16x8*)(Kp + (size_t)(tb * 64 + r) * HDIM + h * DHEAD + c8);
      *(bf16x8*)(&Vs[r][c8]) = *(const bf16x8*)(Vp + ((size_t)h * DHEAD + r) * S_LEN + tb * 64 + c8);
    }
    __syncthreads();

    // S^T = K * Q^T (mfma(K,Q)): sf[j][r] = S[t = tb*64 + j*16 + lq*4 + r][q = l16]
    f32x4 sf[4];
#pragma unroll
    for (int j = 0; j < 4; ++j) sf[j] = (f32x4){0.f, 0.f, 0.f, 0.f};
#pragma unroll
    for (int j = 0; j < 4; ++j)
#pragma unroll
      for (int kk = 0; kk < 2; ++kk) {
        bf16x8 kf = *(const bf16x8*)(&Ks[j * 16 + l16][kk * 32 + lq * 8]);
        sf[j] = MFMA16(kf, qf[kk], sf[j]);
      }

    // per-lane row softmax (q fixed per lane); scores already in log2 domain
    float mx = -1e30f;
#pragma unroll
    for (int j = 0; j < 4; ++j)
#pragma unroll
      for (int r = 0; r < 4; ++r) mx = fmaxf(mx, sf[j][r]);
    mx = fmaxf(mx, __shfl_xor(mx, 16));
    mx = fmaxf(mx, __shfl_xor(mx, 32));

    float mnew = fmaxf(m_run, mx);
    float corr = exp2f(m_run - mnew);
    m_run = mnew;

    float rs = 0.f;
#pragma unroll
    for (int j = 0; j < 4; ++j)
#pragma unroll
      for (int r = 0; r < 4; ++r) {
        float pv = exp2f(sf[j][r] - mnew);
        sf[j][r] = pv;
        rs += pv;
      }
    rs += __shfl_xor(rs, 16);
    rs += __shfl_xor(rs, 32);
    l_run = l_run * corr + rs;
#pragma unroll
    for (int j = 0; j < 4; ++j) {
      oacc[j][0] *= corr; oacc[j][1] *= corr; oacc[j][2] *= corr; oacc[j][3] *= corr;
    }

    // pack P rows -> Ps[wave][q][t] via b64 writes (4 contiguous t per j)
#pragma unroll
    for (int j = 0; j < 4; ++j) {
      bf16x4 pk = { (bf16)sf[j][0], (bf16)sf[j][1], (bf16)sf[j][2], (bf16)sf[j][3] };
      *(bf16x4*)(&Ps[wave][l16][j * 16 + lq * 4]) = pk;
    }
    // within-wave LDS ordering only: drain lgkm, forbid reordering
    asm volatile("s_waitcnt lgkmcnt(0)" ::: "memory");

    bf16x8 pf[2];
    pf[0] = *(const bf16x8*)(&Ps[wave][l16][lq * 8]);
    pf[1] = *(const bf16x8*)(&Ps[wave][l16][32 + lq * 8]);
    // O^T += VT * P : mfma(A=VT rows d, B=P rows q)
#pragma unroll
    for (int j = 0; j < 4; ++j)
#pragma unroll
      for (int kk = 0; kk < 2; ++kk) {
        bf16x8 vtf = *(const bf16x8*)(&Vs[j * 16 + l16][kk * 32 + lq * 8]);
        oacc[j] = MFMA16(vtf, pf[kk], oacc[j]);
      }
  }

  const float inv = 1.0f / l_run;
  const int q = qb * 64 + wave * 16 + l16;
#pragma unroll
  for (int j = 0; j < 4; ++j) {
    size_t off = (size_t)q * HDIM + h * DHEAD + j * 16 + lq * 4;
    float o0 = oacc[j][0] * inv, o1 = oacc[j][1] * inv,
          o2 = oacc[j][2] * inv, o3 = oacc[j][3] * inv;
    if (Ob) {
      bf16x4 ov = { (bf16)o0, (bf16)o1, (bf16)o2, (bf16)o3 };
      *(bf16x4*)(Ob + off) = ov;
    }
    if (Of) {
      float4 ov = { o0, o1, o2, o3 };
      *(float4*)(Of + (size_t)p * oStride + off) = ov;
    }
  }
}

// ---------------- mean over P + build concat matrix -------------------------
__global__ void mean_gate_prep_kernel(const float* __restrict__ rc,   // [2][S][H]
                                      const bf16* __restrict__ outb,  // [S][H]
                                      float* __restrict__ rof,        // [S][H]
                                      bf16* __restrict__ acat,        // [S][2H]
                                      int n) {
  int i = blockIdx.x * blockDim.x + threadIdx.x;
  int stride = gridDim.x * blockDim.x;
  for (; i < n; i += stride) {
    float ro = 0.5f * (rc[i] + rc[i + n]);
    rof[i] = ro;
    int srow = i >> 10, col = i & 1023;
    size_t base = (size_t)srow * 2048;
    acat[base + col] = outb[i];
    acat[base + 1024 + col] = (bf16)ro;
  }
}

// ---------------- final gating ----------------------------------------------
__global__ void final_gate_kernel(const float* __restrict__ outf,
                                  const float* __restrict__ rof,
                                  const float* __restrict__ glog,
                                  float* __restrict__ out, int n) {
  int i = blockIdx.x * blockDim.x + threadIdx.x;
  int stride = gridDim.x * blockDim.x;
  for (; i < n; i += stride) {
    float g = 1.0f / (1.0f + __expf(-glog[i]));
    out[i] = outf[i] * (1.0f - g) + rof[i] * g;
  }
}

// ============================================================================
extern "C" void kernel_launch(void* const* d_in, const int* in_sizes, int n_in,
                              void* d_out, int out_size, void* d_ws, size_t ws_size,
                              hipStream_t stream) {
  const float* hs   = (const float*)d_in[0];
  const float* past = (const float*)d_in[1];
  const float* Wq = (const float*)d_in[2];   const float* bq = (const float*)d_in[3];
  const float* Wk = (const float*)d_in[4];   const float* bk = (const float*)d_in[5];
  const float* Wv = (const float*)d_in[6];   const float* bv = (const float*)d_in[7];
  const float* Wo = (const float*)d_in[8];   const float* bo = (const float*)d_in[9];
  const float* Wrq = (const float*)d_in[10]; const float* brq = (const float*)d_in[11];
  const float* Wrk = (const float*)d_in[12]; const float* brk = (const float*)d_in[13];
  const float* Wrv = (const float*)d_in[14]; const float* brv = (const float*)d_in[15];
  const float* Wg  = (const float*)d_in[16]; const float* bg  = (const float*)d_in[17];

  char* wp = (char*)d_ws;
  auto alloc = [&](size_t bytes) -> void* {
    void* p = (void*)wp;
    wp += (bytes + 255) & ~(size_t)255;
    return p;
  };
  const size_t NE = (size_t)S_LEN * HDIM;  // 2M elements

  bf16* hs_b   = (bf16*)alloc(NE * 2);
  bf16* past_b = (bf16*)alloc(2 * NE * 2);
  bf16* Wqt  = (bf16*)alloc((size_t)HDIM * HDIM * 2);
  bf16* Wkt  = (bf16*)alloc((size_t)HDIM * HDIM * 2);
  bf16* Wvt  = (bf16*)alloc((size_t)HDIM * HDIM * 2);
  bf16* Wot  = (bf16*)alloc((size_t)HDIM * HDIM * 2);
  bf16* Wrqt = (bf16*)alloc((size_t)HDIM * HDIM * 2);
  bf16* Wrkt = (bf16*)alloc((size_t)HDIM * HDIM * 2);
  bf16* Wrvt = (bf16*)alloc((size_t)HDIM * HDIM * 2);
  bf16* Wgt  = (bf16*)alloc((size_t)2 * HDIM * HDIM * 2);  // [1024][2048]
  bf16* q_b   = (bf16*)alloc(NE * 2);
  bf16* k_b   = (bf16*)alloc(NE * 2);
  bf16* v_b   = (bf16*)alloc(NE * 2);
  bf16* vT_b  = (bf16*)alloc(NE * 2);
  bf16* ctx_b = (bf16*)alloc(NE * 2);
  bf16* out_b = (bf16*)alloc(NE * 2);
  float* out_f = (float*)alloc(NE * 4);
  bf16* rq_b  = (bf16*)alloc(NE * 2);
  bf16* rk_b  = (bf16*)alloc(2 * NE * 2);
  bf16* rv_b  = (bf16*)alloc(2 * NE * 2);
  bf16* rvT_b = (bf16*)alloc(2 * NE * 2);
  float* rctx_f = (float*)alloc(2 * NE * 4);
  float* ro_f   = (float*)alloc(NE * 4);
  bf16* acat_b  = (bf16*)alloc(2 * NE * 2);
  float* glog_f = (float*)alloc(NE * 4);

  // 1. convert activations to bf16
  cvt_f32_bf16_kernel<<<2048, 256, 0, stream>>>(hs, hs_b, (int)(NE / 4));
  cvt_f32_bf16_kernel<<<2048, 256, 0, stream>>>(past, past_b, (int)(2 * NE / 4));

  // 2. transpose+convert weights (Bt layout [N][K])
  TrArgs ta{};
  ta.j[0] = {Wq, Wqt};  ta.j[1] = {Wk, Wkt};  ta.j[2] = {Wv, Wvt};
  ta.j[3] = {Wo, Wot};  ta.j[4] = {Wrq, Wrqt}; ta.j[5] = {Wrk, Wrkt};
  ta.j[6] = {Wrv, Wrvt};
  transp_cvt_kernel<<<dim3(32, 32, 7), dim3(32, 8), 0, stream>>>(ta, 1024, 1024);
  TrArgs tg{};
  tg.j[0] = {Wg, Wgt};
  transp_cvt_kernel<<<dim3(32, 64, 1), dim3(32, 8), 0, stream>>>(tg, 2048, 1024);

  // 3. q,k,v (q pre-scaled by QSCALE for exp2-domain softmax)
  GemmArgs g1{};
  g1.j[0] = {hs_b, Wqt, bq, q_b, nullptr, QSCALE};
  g1.j[1] = {hs_b, Wkt, bk, k_b, nullptr, 1.0f};
  g1.j[2] = {hs_b, Wvt, bv, v_b, nullptr, 1.0f};
  gemm_bt_kernel<<<dim3(8, 16, 3), 256, 0, stream>>>(g1, 2048, 1024, 1024);

  // 4. per-head V transpose
  transp_head_kernel<<<dim3(64, 2, 16), dim3(32, 8), 0, stream>>>(v_b, vT_b);

  // 5. self-attention
  flash_attn_kernel<<<dim3(32, 16, 1), 256, 0, stream>>>(
      q_b, k_b, vT_b, ctx_b, nullptr, 0, 0, 0);

  // 6. output projection (bf16 + fp32 outputs)
  GemmArgs g2{};
  g2.j[0] = {ctx_b, Wot, bo, out_b, out_f, 1.0f};
  gemm_bt_kernel<<<dim3(8, 16, 1), 256, 0, stream>>>(g2, 2048, 1024, 1024);

  // 7. rq (pre-scaled), rk(p), rv(p)
  GemmArgs g3{};
  g3.j[0] = {out_b,        Wrqt, brq, rq_b,      nullptr, QSCALE};
  g3.j[1] = {past_b,       Wrkt, brk, rk_b,      nullptr, 1.0f};
  g3.j[2] = {past_b + NE,  Wrkt, brk, rk_b + NE, nullptr, 1.0f};
  g3.j[3] = {past_b,       Wrvt, brv, rv_b,      nullptr, 1.0f};
  g3.j[4] = {past_b + NE,  Wrvt, brv, rv_b + NE, nullptr, 1.0f};
  gemm_bt_kernel<<<dim3(8, 16, 5), 256, 0, stream>>>(g3, 2048, 1024, 1024);

  // 8. per-head rv transposes
  transp_head_kernel<<<dim3(64, 2, 16), dim3(32, 8), 0, stream>>>(rv_b, rvT_b);
  transp_head_kernel<<<dim3(64, 2, 16), dim3(32, 8), 0, stream>>>(rv_b + NE, rvT_b + NE);

  // 9. recursive attention (z = p)
  flash_attn_kernel<<<dim3(32, 16, 2), 256, 0, stream>>>(
      rq_b, rk_b, rvT_b, nullptr, rctx_f, NE, NE, NE);

  // 10. mean over P + concat matrix
  mean_gate_prep_kernel<<<2048, 256, 0, stream>>>(rctx_f, out_b, ro_f, acat_b, (int)NE);

  // 11. gate logits: [S][2H] @ Wg
  GemmArgs g4{};
  g4.j[0] = {acat_b, Wgt, bg, nullptr, glog_f, 1.0f};
  gemm_bt_kernel<<<dim3(8, 16, 1), 256, 0, stream>>>(g4, 2048, 1024, 2048);

  // 12. final gated combine -> d_out (fp32)
  final_gate_kernel<<<2048, 256, 0, stream>>>(out_f, ro_f, glog_f, (float*)d_out, (int)NE);
}

// Round 10
// 434.455 us; speedup vs baseline: 1.1615x; 1.0923x over previous
//
#include <hip/hip_runtime.h>
#include <hip/hip_bf16.h>

// Problem constants (B=1)
#define S_LEN 2048
#define HDIM  1024
#define NHEAD 16
#define DHEAD 64
#define QSCALE  (0.125f * 1.44269504088896340736f)  // 1/sqrt(64) * log2(e), folded into Q

typedef __bf16 bf16;
typedef __bf16 bf16x4 __attribute__((ext_vector_type(4)));
typedef __bf16 bf16x8 __attribute__((ext_vector_type(8)));
typedef float  f32x4  __attribute__((ext_vector_type(4)));

#define MFMA16(a,b,c) __builtin_amdgcn_mfma_f32_16x16x32_bf16((a),(b),(c),0,0,0)

// async global->LDS, 16B per lane; dest is wave-uniform base + lane*16 (m104)
__device__ __forceinline__ void gload16(const bf16* g, bf16* lds_wave_base) {
  __builtin_amdgcn_global_load_lds(
      (const __attribute__((address_space(1))) void*)g,
      (__attribute__((address_space(3))) void*)lds_wave_base, 16, 0, 0);
}

// ---------------- fp32 -> bf16 convert (vectorized) ----------------
__global__ void cvt_f32_bf16_kernel(const float* __restrict__ in,
                                    bf16* __restrict__ out, int n4) {
  int i = blockIdx.x * blockDim.x + threadIdx.x;
  int stride = gridDim.x * blockDim.x;
  for (; i < n4; i += stride) {
    float4 v = ((const float4*)in)[i];
    bf16x4 o = { (bf16)v.x, (bf16)v.y, (bf16)v.z, (bf16)v.w };
    ((bf16x4*)out)[i] = o;
  }
}

// ---------------- transpose + convert: W[rows][cols] f32 -> Wt[cols][rows] bf16
struct TrJob { const float* in; bf16* out; };
struct TrArgs { TrJob j[8]; };

__global__ void transp_cvt_kernel(TrArgs args, int rows, int cols) {
  TrJob t = args.j[blockIdx.z];
  __shared__ float tile[32][33];
  int tx = threadIdx.x, ty = threadIdx.y;
  int c0 = blockIdx.x * 32, r0 = blockIdx.y * 32;
  for (int j = ty; j < 32; j += 8)
    tile[j][tx] = t.in[(size_t)(r0 + j) * cols + c0 + tx];
  __syncthreads();
  for (int j = ty; j < 32; j += 8)
    t.out[(size_t)(c0 + j) * rows + r0 + tx] = (bf16)tile[tx][j];
}

// ---------------- per-head transpose (batched): in[S][H] -> out[NH][DHEAD][S]
struct ThJob { const bf16* in; bf16* out; };
struct ThArgs { ThJob j[4]; };

__global__ void transp_head_kernel(ThArgs args) {
  ThJob t = args.j[blockIdx.z >> 4];
  int h = blockIdx.z & 15;
  __shared__ bf16 tile[32][33];
  int t0 = blockIdx.x * 32, d0 = blockIdx.y * 32;
  int tx = threadIdx.x, ty = threadIdx.y;
  for (int j = ty; j < 32; j += 8)
    tile[j][tx] = t.in[(size_t)(t0 + j) * HDIM + h * DHEAD + d0 + tx];
  __syncthreads();
  for (int j = ty; j < 32; j += 8)
    t.out[((size_t)h * DHEAD + d0 + j) * S_LEN + t0 + tx] = tile[tx][j];
}

// ---------------- batched bf16 GEMM: C[M][N] = (A[M][K] * Bt[N][K]^T + bias)*cscale
// 64x128 tile (grid 2x denser than 128x128), 4 waves (2x2), wave 32x64 = 2x4 frags.
// 2-phase double-buffered global_load_lds staging (T3 minimum recipe, m248).
struct GemmJob { const bf16* A; const bf16* Bt; const float* bias; bf16* Cb; float* Cf; float cscale; };
struct GemmArgs { GemmJob j[8]; };

__launch_bounds__(256)
__global__ void gemm_bt_kernel(GemmArgs args, int M, int N, int K) {
  GemmJob jb = args.j[blockIdx.z];
  const int bn = blockIdx.x, bm = blockIdx.y;
  const int tid = threadIdx.x;
  const int wave = tid >> 6, lane = tid & 63;
  const int wr = wave >> 1, wc = wave & 1;
  const int l16 = lane & 15, lq = lane >> 4;

  __shared__ alignas(16) bf16 As[2][64 * 32];    // linear (global_load_lds)
  __shared__ alignas(16) bf16 Bs[2][128 * 32];

  f32x4 acc[2][4];
#pragma unroll
  for (int i = 0; i < 2; ++i)
#pragma unroll
    for (int j = 0; j < 4; ++j) acc[i][j] = (f32x4){0.f, 0.f, 0.f, 0.f};

  const bf16* Ap = jb.A + (size_t)bm * 64 * K;
  const bf16* Bp = jb.Bt + (size_t)bn * 128 * K;

  // staging map: chunk c0 = wave*64+lane -> row = c0>>2, col8 = (c0&3)*8
  const int c0 = wave * 64 + lane;
  const int r0 = c0 >> 2, c08 = (c0 & 3) << 3;

  auto STAGE = [&](int buf, int kt) {
    gload16(Ap + (size_t)r0 * K + kt + c08, &As[buf][wave * 512]);
    gload16(Bp + (size_t)r0 * K + kt + c08, &Bs[buf][wave * 512]);
    gload16(Bp + (size_t)(r0 + 64) * K + kt + c08, &Bs[buf][2048 + wave * 512]);
  };

  const int NT = K >> 5;
  STAGE(0, 0);
  __syncthreads();                       // vmcnt(0) drain + barrier

  for (int t = 0; t < NT; ++t) {
    const int cur = t & 1;
    const int ktn = (t + 1 < NT) ? (t + 1) * 32 : t * 32;  // clamp (redundant last)
    STAGE(cur ^ 1, ktn);                 // issue next tile BEFORE compute

    bf16x8 af[2], bfr[4];
#pragma unroll
    for (int i = 0; i < 2; ++i)
      af[i] = *(const bf16x8*)(&As[cur][(wr * 32 + i * 16 + l16) * 32 + lq * 8]);
#pragma unroll
    for (int j = 0; j < 4; ++j)
      bfr[j] = *(const bf16x8*)(&Bs[cur][(wc * 64 + j * 16 + l16) * 32 + lq * 8]);
#pragma unroll
    for (int i = 0; i < 2; ++i)
#pragma unroll
      for (int j = 0; j < 4; ++j)
        acc[i][j] = MFMA16(af[i], bfr[j], acc[i][j]);

    __syncthreads();                     // single vmcnt(0)+barrier per K-step
  }

  // epilogue: C row = lq*4+r, col = l16 (m89-verified)
#pragma unroll
  for (int i = 0; i < 2; ++i) {
#pragma unroll
    for (int j = 0; j < 4; ++j) {
      int row0 = bm * 64 + wr * 32 + i * 16 + lq * 4;
      int col  = bn * 128 + wc * 64 + j * 16 + l16;
      float bv = jb.bias ? jb.bias[col] : 0.0f;
#pragma unroll
      for (int r = 0; r < 4; ++r) {
        float v = (acc[i][j][r] + bv) * jb.cscale;
        size_t off = (size_t)(row0 + r) * N + col;
        if (jb.Cb) jb.Cb[off] = (bf16)v;
        if (jb.Cf) jb.Cf[off] = v;
      }
    }
  }
}

// ---------------- flash attention, swapped-QK^T, double-buffered K/V --------
// Q [S][H] bf16 PRE-SCALED by QSCALE; K [S][H]; VT [NH][DHEAD][S].
// grid: (S/64, NH, P). Lane owns one q-row (q=l16); softmax in-register;
// P round-trip per-wave (no barrier); PV computes O^T = VT * P.
// T14 async-stage: issue tile t+1 loads before compute(t), LDS-write after,
// ONE barrier per tile.
__launch_bounds__(256)
__global__ void flash_attn_kernel(const bf16* __restrict__ Q,
                                  const bf16* __restrict__ Kin,
                                  const bf16* __restrict__ VT,
                                  bf16* __restrict__ Ob,
                                  float* __restrict__ Of,
                                  size_t kStride, size_t vStride, size_t oStride) {
  const int qb = blockIdx.x, h = blockIdx.y, p = blockIdx.z;
  const bf16* Kp = Kin + (size_t)p * kStride;
  const bf16* Vp = VT + (size_t)p * vStride;
  const int tid = threadIdx.x;
  const int wave = tid >> 6, lane = tid & 63;
  const int l16 = lane & 15, lq = lane >> 4;

  __shared__ alignas(16) bf16 Ks[2][64][72];    // [t][d]
  __shared__ alignas(16) bf16 Vs[2][64][72];    // [d][t]
  __shared__ alignas(16) bf16 Ps[4][16][72];    // per-wave [q][t]

  // staging indices (per wave: 2 chunks of each array)
  const int i0 = tid, i1 = tid + 256;
  const int ra = i0 >> 3, ca = (i0 & 7) << 3;
  const int rb = i1 >> 3, cb = (i1 & 7) << 3;

  bf16x8 krg[2], vrg[2];
  auto LOAD_TILE = [&](int tb) {
    krg[0] = *(const bf16x8*)(Kp + (size_t)(tb * 64 + ra) * HDIM + h * DHEAD + ca);
    krg[1] = *(const bf16x8*)(Kp + (size_t)(tb * 64 + rb) * HDIM + h * DHEAD + cb);
    vrg[0] = *(const bf16x8*)(Vp + ((size_t)h * DHEAD + ra) * S_LEN + tb * 64 + ca);
    vrg[1] = *(const bf16x8*)(Vp + ((size_t)h * DHEAD + rb) * S_LEN + tb * 64 + cb);
  };
  auto STORE_TILE = [&](int buf) {
    *(bf16x8*)(&Ks[buf][ra][ca]) = krg[0];
    *(bf16x8*)(&Ks[buf][rb][cb]) = krg[1];
    *(bf16x8*)(&Vs[buf][ra][ca]) = vrg[0];
    *(bf16x8*)(&Vs[buf][rb][cb]) = vrg[1];
  };

  // Q as B-frag: lane holds Q[q = wave*16+l16][d = kk*32 + lq*8 ..+7]
  bf16x8 qf[2];
  {
    const bf16* qptr = Q + (size_t)(qb * 64 + wave * 16 + l16) * HDIM + h * DHEAD + lq * 8;
    qf[0] = *(const bf16x8*)qptr;
    qf[1] = *(const bf16x8*)(qptr + 32);
  }

  float m_run = -1e30f, l_run = 0.f;
  f32x4 oacc[4];                                // O^T: d = j*16+lq*4+r, q = l16
#pragma unroll
  for (int j = 0; j < 4; ++j) oacc[j] = (f32x4){0.f, 0.f, 0.f, 0.f};

  const int NT = S_LEN / 64;
  LOAD_TILE(0);
  STORE_TILE(0);
  __syncthreads();

  for (int tb = 0; tb < NT; ++tb) {
    const int cur = tb & 1;
    const bool more = (tb + 1 < NT);
    if (more) LOAD_TILE(tb + 1);        // issue early; lands under compute

    // S^T = K * Q^T: sf[j][r] = S[t = tb*64 + j*16 + lq*4 + r][q = l16]
    f32x4 sf[4];
#pragma unroll
    for (int j = 0; j < 4; ++j) sf[j] = (f32x4){0.f, 0.f, 0.f, 0.f};
#pragma unroll
    for (int j = 0; j < 4; ++j)
#pragma unroll
      for (int kk = 0; kk < 2; ++kk) {
        bf16x8 kf = *(const bf16x8*)(&Ks[cur][j * 16 + l16][kk * 32 + lq * 8]);
        sf[j] = MFMA16(kf, qf[kk], sf[j]);
      }

    // per-lane row softmax (q fixed per lane); scores in log2 domain
    float mx = -1e30f;
#pragma unroll
    for (int j = 0; j < 4; ++j)
#pragma unroll
      for (int r = 0; r < 4; ++r) mx = fmaxf(mx, sf[j][r]);
    mx = fmaxf(mx, __shfl_xor(mx, 16));
    mx = fmaxf(mx, __shfl_xor(mx, 32));

    float mnew = fmaxf(m_run, mx);
    float corr = exp2f(m_run - mnew);
    m_run = mnew;

    float rs = 0.f;
#pragma unroll
    for (int j = 0; j < 4; ++j)
#pragma unroll
      for (int r = 0; r < 4; ++r) {
        float pv = exp2f(sf[j][r] - mnew);
        sf[j][r] = pv;
        rs += pv;
      }
    rs += __shfl_xor(rs, 16);
    rs += __shfl_xor(rs, 32);
    l_run = l_run * corr + rs;
#pragma unroll
    for (int j = 0; j < 4; ++j) {
      oacc[j][0] *= corr; oacc[j][1] *= corr; oacc[j][2] *= corr; oacc[j][3] *= corr;
    }

    // pack P rows -> Ps[wave][q][t] via b64 writes (4 contiguous t per j)
#pragma unroll
    for (int j = 0; j < 4; ++j) {
      bf16x4 pk = { (bf16)sf[j][0], (bf16)sf[j][1], (bf16)sf[j][2], (bf16)sf[j][3] };
      *(bf16x4*)(&Ps[wave][l16][j * 16 + lq * 4]) = pk;
    }
    // within-wave LDS ordering only (no barrier needed)
    asm volatile("s_waitcnt lgkmcnt(0)" ::: "memory");

    bf16x8 pf[2];
    pf[0] = *(const bf16x8*)(&Ps[wave][l16][lq * 8]);
    pf[1] = *(const bf16x8*)(&Ps[wave][l16][32 + lq * 8]);
    // O^T += VT * P
#pragma unroll
    for (int j = 0; j < 4; ++j)
#pragma unroll
      for (int kk = 0; kk < 2; ++kk) {
        bf16x8 vtf = *(const bf16x8*)(&Vs[cur][j * 16 + l16][kk * 32 + lq * 8]);
        oacc[j] = MFMA16(vtf, pf[kk], oacc[j]);
      }

    if (more) {
      STORE_TILE(cur ^ 1);              // compiler inserts vmcnt wait here
      __syncthreads();                  // ONE barrier per tile
    }
  }

  const float inv = 1.0f / l_run;
  const int q = qb * 64 + wave * 16 + l16;
#pragma unroll
  for (int j = 0; j < 4; ++j) {
    size_t off = (size_t)q * HDIM + h * DHEAD + j * 16 + lq * 4;
    float o0 = oacc[j][0] * inv, o1 = oacc[j][1] * inv,
          o2 = oacc[j][2] * inv, o3 = oacc[j][3] * inv;
    if (Ob) {
      bf16x4 ov = { (bf16)o0, (bf16)o1, (bf16)o2, (bf16)o3 };
      *(bf16x4*)(Ob + off) = ov;
    }
    if (Of) {
      float4 ov = { o0, o1, o2, o3 };
      *(float4*)(Of + (size_t)p * oStride + off) = ov;
    }
  }
}

// ---------------- mean over P + build concat matrix -------------------------
__global__ void mean_gate_prep_kernel(const float* __restrict__ rc,   // [2][S][H]
                                      const bf16* __restrict__ outb,  // [S][H]
                                      float* __restrict__ rof,        // [S][H]
                                      bf16* __restrict__ acat,        // [S][2H]
                                      int n) {
  int i = blockIdx.x * blockDim.x + threadIdx.x;
  int stride = gridDim.x * blockDim.x;
  for (; i < n; i += stride) {
    float ro = 0.5f * (rc[i] + rc[i + n]);
    rof[i] = ro;
    int srow = i >> 10, col = i & 1023;
    size_t base = (size_t)srow * 2048;
    acat[base + col] = outb[i];
    acat[base + 1024 + col] = (bf16)ro;
  }
}

// ---------------- final gating ----------------------------------------------
__global__ void final_gate_kernel(const float* __restrict__ outf,
                                  const float* __restrict__ rof,
                                  const float* __restrict__ glog,
                                  float* __restrict__ out, int n) {
  int i = blockIdx.x * blockDim.x + threadIdx.x;
  int stride = gridDim.x * blockDim.x;
  for (; i < n; i += stride) {
    float g = 1.0f / (1.0f + __expf(-glog[i]));
    out[i] = outf[i] * (1.0f - g) + rof[i] * g;
  }
}

// ============================================================================
extern "C" void kernel_launch(void* const* d_in, const int* in_sizes, int n_in,
                              void* d_out, int out_size, void* d_ws, size_t ws_size,
                              hipStream_t stream) {
  const float* hs   = (const float*)d_in[0];
  const float* past = (const float*)d_in[1];
  const float* Wq = (const float*)d_in[2];   const float* bq = (const float*)d_in[3];
  const float* Wk = (const float*)d_in[4];   const float* bk = (const float*)d_in[5];
  const float* Wv = (const float*)d_in[6];   const float* bv = (const float*)d_in[7];
  const float* Wo = (const float*)d_in[8];   const float* bo = (const float*)d_in[9];
  const float* Wrq = (const float*)d_in[10]; const float* brq = (const float*)d_in[11];
  const float* Wrk = (const float*)d_in[12]; const float* brk = (const float*)d_in[13];
  const float* Wrv = (const float*)d_in[14]; const float* brv = (const float*)d_in[15];
  const float* Wg  = (const float*)d_in[16]; const float* bg  = (const float*)d_in[17];

  char* wp = (char*)d_ws;
  auto alloc = [&](size_t bytes) -> void* {
    void* p = (void*)wp;
    wp += (bytes + 255) & ~(size_t)255;
    return p;
  };
  const size_t NE = (size_t)S_LEN * HDIM;  // 2M elements

  bf16* hs_b   = (bf16*)alloc(NE * 2);
  bf16* past_b = (bf16*)alloc(2 * NE * 2);
  bf16* Wqt  = (bf16*)alloc((size_t)HDIM * HDIM * 2);
  bf16* Wkt  = (bf16*)alloc((size_t)HDIM * HDIM * 2);
  bf16* Wvt  = (bf16*)alloc((size_t)HDIM * HDIM * 2);
  bf16* Wot  = (bf16*)alloc((size_t)HDIM * HDIM * 2);
  bf16* Wrqt = (bf16*)alloc((size_t)HDIM * HDIM * 2);
  bf16* Wrkt = (bf16*)alloc((size_t)HDIM * HDIM * 2);
  bf16* Wrvt = (bf16*)alloc((size_t)HDIM * HDIM * 2);
  bf16* Wgt  = (bf16*)alloc((size_t)2 * HDIM * HDIM * 2);  // [1024][2048]
  bf16* q_b   = (bf16*)alloc(NE * 2);
  bf16* k_b   = (bf16*)alloc(NE * 2);
  bf16* v_b   = (bf16*)alloc(NE * 2);
  bf16* vT_b  = (bf16*)alloc(NE * 2);
  bf16* ctx_b = (bf16*)alloc(NE * 2);
  bf16* out_b = (bf16*)alloc(NE * 2);
  float* out_f = (float*)alloc(NE * 4);
  bf16* rq_b  = (bf16*)alloc(NE * 2);
  bf16* rk_b  = (bf16*)alloc(2 * NE * 2);
  bf16* rv_b  = (bf16*)alloc(2 * NE * 2);
  bf16* rvT_b = (bf16*)alloc(2 * NE * 2);
  float* rctx_f = (float*)alloc(2 * NE * 4);
  float* ro_f   = (float*)alloc(NE * 4);
  bf16* acat_b  = (bf16*)alloc(2 * NE * 2);
  float* glog_f = (float*)alloc(NE * 4);

  // 1. convert activations to bf16
  cvt_f32_bf16_kernel<<<2048, 256, 0, stream>>>(hs, hs_b, (int)(NE / 4));
  cvt_f32_bf16_kernel<<<2048, 256, 0, stream>>>(past, past_b, (int)(2 * NE / 4));

  // 2. transpose+convert weights (Bt layout [N][K])
  TrArgs ta{};
  ta.j[0] = {Wq, Wqt};  ta.j[1] = {Wk, Wkt};  ta.j[2] = {Wv, Wvt};
  ta.j[3] = {Wo, Wot};  ta.j[4] = {Wrq, Wrqt}; ta.j[5] = {Wrk, Wrkt};
  ta.j[6] = {Wrv, Wrvt};
  transp_cvt_kernel<<<dim3(32, 32, 7), dim3(32, 8), 0, stream>>>(ta, 1024, 1024);
  TrArgs tg{};
  tg.j[0] = {Wg, Wgt};
  transp_cvt_kernel<<<dim3(32, 64, 1), dim3(32, 8), 0, stream>>>(tg, 2048, 1024);

  // 3. big batch: q,k,v + rk(p),rv(p) (only need hs/past) — 7 jobs, 1792 wgs
  GemmArgs g1{};
  g1.j[0] = {hs_b,        Wqt,  bq,  q_b,        nullptr, QSCALE};
  g1.j[1] = {hs_b,        Wkt,  bk,  k_b,        nullptr, 1.0f};
  g1.j[2] = {hs_b,        Wvt,  bv,  v_b,        nullptr, 1.0f};
  g1.j[3] = {past_b,      Wrkt, brk, rk_b,       nullptr, 1.0f};
  g1.j[4] = {past_b + NE, Wrkt, brk, rk_b + NE,  nullptr, 1.0f};
  g1.j[5] = {past_b,      Wrvt, brv, rv_b,       nullptr, 1.0f};
  g1.j[6] = {past_b + NE, Wrvt, brv, rv_b + NE,  nullptr, 1.0f};
  gemm_bt_kernel<<<dim3(8, 32, 7), 256, 0, stream>>>(g1, 2048, 1024, 1024);

  // 4. per-head transposes: v, rv0, rv1 (batched, z = 3*16)
  ThArgs th{};
  th.j[0] = {v_b, vT_b};
  th.j[1] = {rv_b, rvT_b};
  th.j[2] = {rv_b + NE, rvT_b + NE};
  transp_head_kernel<<<dim3(64, 2, 48), dim3(32, 8), 0, stream>>>(th);

  // 5. self-attention
  flash_attn_kernel<<<dim3(32, 16, 1), 256, 0, stream>>>(
      q_b, k_b, vT_b, ctx_b, nullptr, 0, 0, 0);

  // 6. output projection (bf16 + fp32 outputs)
  GemmArgs g2{};
  g2.j[0] = {ctx_b, Wot, bo, out_b, out_f, 1.0f};
  gemm_bt_kernel<<<dim3(8, 32, 1), 256, 0, stream>>>(g2, 2048, 1024, 1024);

  // 7. rq (pre-scaled)
  GemmArgs g3{};
  g3.j[0] = {out_b, Wrqt, brq, rq_b, nullptr, QSCALE};
  gemm_bt_kernel<<<dim3(8, 32, 1), 256, 0, stream>>>(g3, 2048, 1024, 1024);

  // 8. recursive attention (z = p)
  flash_attn_kernel<<<dim3(32, 16, 2), 256, 0, stream>>>(
      rq_b, rk_b, rvT_b, nullptr, rctx_f, NE, NE, NE);

  // 9. mean over P + concat matrix
  mean_gate_prep_kernel<<<2048, 256, 0, stream>>>(rctx_f, out_b, ro_f, acat_b, (int)NE);

  // 10. gate logits: [S][2H] @ Wg
  GemmArgs g4{};
  g4.j[0] = {acat_b, Wgt, bg, nullptr, glog_f, 1.0f};
  gemm_bt_kernel<<<dim3(8, 32, 1), 256, 0, stream>>>(g4, 2048, 1024, 2048);

  // 11. final gated combine -> d_out (fp32)
  final_gate_kernel<<<2048, 256, 0, stream>>>(out_f, ro_f, glog_f, (float*)d_out, (int)NE);
}

// Round 11
// 416.645 us; speedup vs baseline: 1.2112x; 1.0427x over previous
//
#include <hip/hip_runtime.h>
#include <hip/hip_bf16.h>

// Problem constants (B=1)
#define S_LEN 2048
#define HDIM  1024
#define NHEAD 16
#define DHEAD 64
#define QSCALE  (0.125f * 1.44269504088896340736f)  // 1/sqrt(64) * log2(e), folded into Q
#define DEFER_THR 8.0f                               // T13 defer-max threshold

typedef __bf16 bf16;
typedef __bf16 bf16x4 __attribute__((ext_vector_type(4)));
typedef __bf16 bf16x8 __attribute__((ext_vector_type(8)));
typedef float  f32x4  __attribute__((ext_vector_type(4)));

#define MFMA16(a,b,c) __builtin_amdgcn_mfma_f32_16x16x32_bf16((a),(b),(c),0,0,0)

// async global->LDS, 16B per lane; dest is wave-uniform base + lane*16 (m104)
__device__ __forceinline__ void gload16(const bf16* g, bf16* lds_wave_base) {
  __builtin_amdgcn_global_load_lds(
      (const __attribute__((address_space(1))) void*)g,
      (__attribute__((address_space(3))) void*)lds_wave_base, 16, 0, 0);
}

// ---------------- fp32 -> bf16 convert (vectorized) ----------------
__global__ void cvt_f32_bf16_kernel(const float* __restrict__ in,
                                    bf16* __restrict__ out, int n4) {
  int i = blockIdx.x * blockDim.x + threadIdx.x;
  int stride = gridDim.x * blockDim.x;
  for (; i < n4; i += stride) {
    float4 v = ((const float4*)in)[i];
    bf16x4 o = { (bf16)v.x, (bf16)v.y, (bf16)v.z, (bf16)v.w };
    ((bf16x4*)out)[i] = o;
  }
}

// ---------------- transpose + convert: W[rows][cols] f32 -> Wt[cols][rows] bf16
struct TrJob { const float* in; bf16* out; };
struct TrArgs { TrJob j[8]; };

__global__ void transp_cvt_kernel(TrArgs args, int rows, int cols) {
  TrJob t = args.j[blockIdx.z];
  __shared__ float tile[32][33];
  int tx = threadIdx.x, ty = threadIdx.y;
  int c0 = blockIdx.x * 32, r0 = blockIdx.y * 32;
  for (int j = ty; j < 32; j += 8)
    tile[j][tx] = t.in[(size_t)(r0 + j) * cols + c0 + tx];
  __syncthreads();
  for (int j = ty; j < 32; j += 8)
    t.out[(size_t)(c0 + j) * rows + r0 + tx] = (bf16)tile[tx][j];
}

// ---------------- per-head transpose (batched): in[S][H] -> out[NH][DHEAD][S]
struct ThJob { const bf16* in; bf16* out; };
struct ThArgs { ThJob j[4]; };

__global__ void transp_head_kernel(ThArgs args) {
  ThJob t = args.j[blockIdx.z >> 4];
  int h = blockIdx.z & 15;
  __shared__ bf16 tile[32][33];
  int t0 = blockIdx.x * 32, d0 = blockIdx.y * 32;
  int tx = threadIdx.x, ty = threadIdx.y;
  for (int j = ty; j < 32; j += 8)
    tile[j][tx] = t.in[(size_t)(t0 + j) * HDIM + h * DHEAD + d0 + tx];
  __syncthreads();
  for (int j = ty; j < 32; j += 8)
    t.out[((size_t)h * DHEAD + d0 + j) * S_LEN + t0 + tx] = tile[tx][j];
}

// ---------------- batched bf16 GEMM: C[M][N] = (A[M][K] * Bt[N][K]^T + bias)*cscale
// 64x128 tile, 4 waves (2x2), wave 32x64 = 2x4 frags.
// 2-phase double-buffered global_load_lds staging (T3 minimum recipe, m248).
struct GemmJob { const bf16* A; const bf16* Bt; const float* bias; bf16* Cb; float* Cf; float cscale; };
struct GemmArgs { GemmJob j[8]; };

__launch_bounds__(256)
__global__ void gemm_bt_kernel(GemmArgs args, int M, int N, int K) {
  GemmJob jb = args.j[blockIdx.z];
  const int bn = blockIdx.x, bm = blockIdx.y;
  const int tid = threadIdx.x;
  const int wave = tid >> 6, lane = tid & 63;
  const int wr = wave >> 1, wc = wave & 1;
  const int l16 = lane & 15, lq = lane >> 4;

  __shared__ alignas(16) bf16 As[2][64 * 32];    // linear (global_load_lds)
  __shared__ alignas(16) bf16 Bs[2][128 * 32];

  f32x4 acc[2][4];
#pragma unroll
  for (int i = 0; i < 2; ++i)
#pragma unroll
    for (int j = 0; j < 4; ++j) acc[i][j] = (f32x4){0.f, 0.f, 0.f, 0.f};

  const bf16* Ap = jb.A + (size_t)bm * 64 * K;
  const bf16* Bp = jb.Bt + (size_t)bn * 128 * K;

  // staging map: chunk c0 = wave*64+lane -> row = c0>>2, col8 = (c0&3)*8
  const int c0 = wave * 64 + lane;
  const int r0 = c0 >> 2, c08 = (c0 & 3) << 3;

  auto STAGE = [&](int buf, int kt) {
    gload16(Ap + (size_t)r0 * K + kt + c08, &As[buf][wave * 512]);
    gload16(Bp + (size_t)r0 * K + kt + c08, &Bs[buf][wave * 512]);
    gload16(Bp + (size_t)(r0 + 64) * K + kt + c08, &Bs[buf][2048 + wave * 512]);
  };

  const int NT = K >> 5;
  STAGE(0, 0);
  __syncthreads();                       // vmcnt(0) drain + barrier

  for (int t = 0; t < NT; ++t) {
    const int cur = t & 1;
    const int ktn = (t + 1 < NT) ? (t + 1) * 32 : t * 32;  // clamp (redundant last)
    STAGE(cur ^ 1, ktn);                 // issue next tile BEFORE compute

    bf16x8 af[2], bfr[4];
#pragma unroll
    for (int i = 0; i < 2; ++i)
      af[i] = *(const bf16x8*)(&As[cur][(wr * 32 + i * 16 + l16) * 32 + lq * 8]);
#pragma unroll
    for (int j = 0; j < 4; ++j)
      bfr[j] = *(const bf16x8*)(&Bs[cur][(wc * 64 + j * 16 + l16) * 32 + lq * 8]);
#pragma unroll
    for (int i = 0; i < 2; ++i)
#pragma unroll
      for (int j = 0; j < 4; ++j)
        acc[i][j] = MFMA16(af[i], bfr[j], acc[i][j]);

    __syncthreads();                     // single vmcnt(0)+barrier per K-step
  }

  // epilogue: C row = lq*4+r, col = l16 (m89-verified)
#pragma unroll
  for (int i = 0; i < 2; ++i) {
#pragma unroll
    for (int j = 0; j < 4; ++j) {
      int row0 = bm * 64 + wr * 32 + i * 16 + lq * 4;
      int col  = bn * 128 + wc * 64 + j * 16 + l16;
      float bv = jb.bias ? jb.bias[col] : 0.0f;
#pragma unroll
      for (int r = 0; r < 4; ++r) {
        float v = (acc[i][j][r] + bv) * jb.cscale;
        size_t off = (size_t)(row0 + r) * N + col;
        if (jb.Cb) jb.Cb[off] = (bf16)v;
        if (jb.Cf) jb.Cf[off] = v;
      }
    }
  }
}

// ---------------- flash attention (QBLK=64), swapped-QK^T, dbuf K/V ---------
// Used for SELF attention (grid 32x16x1 = 512 blocks -> 2 blocks/CU).
__launch_bounds__(256)
__global__ void flash_attn_kernel(const bf16* __restrict__ Q,
                                  const bf16* __restrict__ Kin,
                                  const bf16* __restrict__ VT,
                                  bf16* __restrict__ Ob,
                                  float* __restrict__ Of,
                                  size_t kStride, size_t vStride, size_t oStride) {
  const int qb = blockIdx.x, h = blockIdx.y, p = blockIdx.z;
  const bf16* Kp = Kin + (size_t)p * kStride;
  const bf16* Vp = VT + (size_t)p * vStride;
  const int tid = threadIdx.x;
  const int wave = tid >> 6, lane = tid & 63;
  const int l16 = lane & 15, lq = lane >> 4;

  __shared__ alignas(16) bf16 Ks[2][64][72];    // [t][d]
  __shared__ alignas(16) bf16 Vs[2][64][72];    // [d][t]
  __shared__ alignas(16) bf16 Ps[4][16][72];    // per-wave [q][t]

  const int i0 = tid, i1 = tid + 256;
  const int ra = i0 >> 3, ca = (i0 & 7) << 3;
  const int rb = i1 >> 3, cb = (i1 & 7) << 3;

  bf16x8 krg[2], vrg[2];
  auto LOAD_TILE = [&](int tb) {
    krg[0] = *(const bf16x8*)(Kp + (size_t)(tb * 64 + ra) * HDIM + h * DHEAD + ca);
    krg[1] = *(const bf16x8*)(Kp + (size_t)(tb * 64 + rb) * HDIM + h * DHEAD + cb);
    vrg[0] = *(const bf16x8*)(Vp + ((size_t)h * DHEAD + ra) * S_LEN + tb * 64 + ca);
    vrg[1] = *(const bf16x8*)(Vp + ((size_t)h * DHEAD + rb) * S_LEN + tb * 64 + cb);
  };
  auto STORE_TILE = [&](int buf) {
    *(bf16x8*)(&Ks[buf][ra][ca]) = krg[0];
    *(bf16x8*)(&Ks[buf][rb][cb]) = krg[1];
    *(bf16x8*)(&Vs[buf][ra][ca]) = vrg[0];
    *(bf16x8*)(&Vs[buf][rb][cb]) = vrg[1];
  };

  bf16x8 qf[2];
  {
    const bf16* qptr = Q + (size_t)(qb * 64 + wave * 16 + l16) * HDIM + h * DHEAD + lq * 8;
    qf[0] = *(const bf16x8*)qptr;
    qf[1] = *(const bf16x8*)(qptr + 32);
  }

  float m_run = -1e30f, l_run = 0.f;
  f32x4 oacc[4];
#pragma unroll
  for (int j = 0; j < 4; ++j) oacc[j] = (f32x4){0.f, 0.f, 0.f, 0.f};

  const int NT = S_LEN / 64;
  LOAD_TILE(0);
  STORE_TILE(0);
  __syncthreads();

  for (int tb = 0; tb < NT; ++tb) {
    const int cur = tb & 1;
    const bool more = (tb + 1 < NT);
    if (more) LOAD_TILE(tb + 1);

    f32x4 sf[4];
#pragma unroll
    for (int j = 0; j < 4; ++j) sf[j] = (f32x4){0.f, 0.f, 0.f, 0.f};
#pragma unroll
    for (int j = 0; j < 4; ++j)
#pragma unroll
      for (int kk = 0; kk < 2; ++kk) {
        bf16x8 kf = *(const bf16x8*)(&Ks[cur][j * 16 + l16][kk * 32 + lq * 8]);
        sf[j] = MFMA16(kf, qf[kk], sf[j]);
      }

    float mx = -1e30f;
#pragma unroll
    for (int j = 0; j < 4; ++j)
#pragma unroll
      for (int r = 0; r < 4; ++r) mx = fmaxf(mx, sf[j][r]);
    mx = fmaxf(mx, __shfl_xor(mx, 16));
    mx = fmaxf(mx, __shfl_xor(mx, 32));

    // T13 defer-max: skip rescale when bounded (exp2(8)=256 headroom)
    if (!__all(mx <= m_run + DEFER_THR)) {
      float mnew = fmaxf(m_run, mx);
      float corr = exp2f(m_run - mnew);
      m_run = mnew;
      l_run *= corr;
#pragma unroll
      for (int j = 0; j < 4; ++j) {
        oacc[j][0] *= corr; oacc[j][1] *= corr; oacc[j][2] *= corr; oacc[j][3] *= corr;
      }
    }

    float rs = 0.f;
#pragma unroll
    for (int j = 0; j < 4; ++j)
#pragma unroll
      for (int r = 0; r < 4; ++r) {
        float pv = exp2f(sf[j][r] - m_run);
        sf[j][r] = pv;
        rs += pv;
      }
    rs += __shfl_xor(rs, 16);
    rs += __shfl_xor(rs, 32);
    l_run += rs;

#pragma unroll
    for (int j = 0; j < 4; ++j) {
      bf16x4 pk = { (bf16)sf[j][0], (bf16)sf[j][1], (bf16)sf[j][2], (bf16)sf[j][3] };
      *(bf16x4*)(&Ps[wave][l16][j * 16 + lq * 4]) = pk;
    }
    asm volatile("s_waitcnt lgkmcnt(0)" ::: "memory");

    bf16x8 pf[2];
    pf[0] = *(const bf16x8*)(&Ps[wave][l16][lq * 8]);
    pf[1] = *(const bf16x8*)(&Ps[wave][l16][32 + lq * 8]);
#pragma unroll
    for (int j = 0; j < 4; ++j)
#pragma unroll
      for (int kk = 0; kk < 2; ++kk) {
        bf16x8 vtf = *(const bf16x8*)(&Vs[cur][j * 16 + l16][kk * 32 + lq * 8]);
        oacc[j] = MFMA16(vtf, pf[kk], oacc[j]);
      }

    if (more) {
      STORE_TILE(cur ^ 1);
      __syncthreads();
    }
  }

  const float inv = 1.0f / l_run;
  const int q = qb * 64 + wave * 16 + l16;
#pragma unroll
  for (int j = 0; j < 4; ++j) {
    size_t off = (size_t)q * HDIM + h * DHEAD + j * 16 + lq * 4;
    float o0 = oacc[j][0] * inv, o1 = oacc[j][1] * inv,
          o2 = oacc[j][2] * inv, o3 = oacc[j][3] * inv;
    if (Ob) {
      bf16x4 ov = { (bf16)o0, (bf16)o1, (bf16)o2, (bf16)o3 };
      *(bf16x4*)(Ob + off) = ov;
    }
    if (Of) {
      float4 ov = { o0, o1, o2, o3 };
      *(float4*)(Of + (size_t)p * oStride + off) = ov;
    }
  }
}

// ---------------- flash attention v2 (QBLK=128): 2 q-subtiles per wave ------
// Used for RECURSIVE attention (grid 16x16x2 = 512 blocks -> 2 blocks/CU).
// kf/vtf LDS reads are shared across both q-subtiles: 20 ds_read_b128 per
// 32q x 64t of work vs 36 in the QBLK=64 kernel (-44% LDS pipe).
__launch_bounds__(256)
__global__ void flash_attn2_kernel(const bf16* __restrict__ Q,
                                   const bf16* __restrict__ Kin,
                                   const bf16* __restrict__ VT,
                                   bf16* __restrict__ Ob,
                                   float* __restrict__ Of,
                                   size_t kStride, size_t vStride, size_t oStride) {
  const int qb = blockIdx.x, h = blockIdx.y, p = blockIdx.z;
  const bf16* Kp = Kin + (size_t)p * kStride;
  const bf16* Vp = VT + (size_t)p * vStride;
  const int tid = threadIdx.x;
  const int wave = tid >> 6, lane = tid & 63;
  const int l16 = lane & 15, lq = lane >> 4;

  __shared__ alignas(16) bf16 Ks[2][64][72];       // [t][d]
  __shared__ alignas(16) bf16 Vs[2][64][72];       // [d][t]
  __shared__ alignas(16) bf16 Ps[4][2][16][72];    // per-wave, per-subtile [q][t]

  const int i0 = tid, i1 = tid + 256;
  const int ra = i0 >> 3, ca = (i0 & 7) << 3;
  const int rb = i1 >> 3, cb = (i1 & 7) << 3;

  bf16x8 krg[2], vrg[2];
  auto LOAD_TILE = [&](int tb) {
    krg[0] = *(const bf16x8*)(Kp + (size_t)(tb * 64 + ra) * HDIM + h * DHEAD + ca);
    krg[1] = *(const bf16x8*)(Kp + (size_t)(tb * 64 + rb) * HDIM + h * DHEAD + cb);
    vrg[0] = *(const bf16x8*)(Vp + ((size_t)h * DHEAD + ra) * S_LEN + tb * 64 + ca);
    vrg[1] = *(const bf16x8*)(Vp + ((size_t)h * DHEAD + rb) * S_LEN + tb * 64 + cb);
  };
  auto STORE_TILE = [&](int buf) {
    *(bf16x8*)(&Ks[buf][ra][ca]) = krg[0];
    *(bf16x8*)(&Ks[buf][rb][cb]) = krg[1];
    *(bf16x8*)(&Vs[buf][ra][ca]) = vrg[0];
    *(bf16x8*)(&Vs[buf][rb][cb]) = vrg[1];
  };

  // Q frags for 2 subtiles: q = qb*128 + wave*32 + s*16 + l16
  bf16x8 qf[2][2];
#pragma unroll
  for (int s = 0; s < 2; ++s) {
    const bf16* qptr = Q + (size_t)(qb * 128 + wave * 32 + s * 16 + l16) * HDIM + h * DHEAD + lq * 8;
    qf[s][0] = *(const bf16x8*)qptr;
    qf[s][1] = *(const bf16x8*)(qptr + 32);
  }

  float m_run[2] = { -1e30f, -1e30f }, l_run[2] = { 0.f, 0.f };
  f32x4 oacc[2][4];
#pragma unroll
  for (int s = 0; s < 2; ++s)
#pragma unroll
    for (int j = 0; j < 4; ++j) oacc[s][j] = (f32x4){0.f, 0.f, 0.f, 0.f};

  const int NT = S_LEN / 64;
  LOAD_TILE(0);
  STORE_TILE(0);
  __syncthreads();

  for (int tb = 0; tb < NT; ++tb) {
    const int cur = tb & 1;
    const bool more = (tb + 1 < NT);
    if (more) LOAD_TILE(tb + 1);

    // S^T for both subtiles; kf read ONCE per (j,kk)
    f32x4 sf[2][4];
#pragma unroll
    for (int s = 0; s < 2; ++s)
#pragma unroll
      for (int j = 0; j < 4; ++j) sf[s][j] = (f32x4){0.f, 0.f, 0.f, 0.f};
#pragma unroll
    for (int j = 0; j < 4; ++j)
#pragma unroll
      for (int kk = 0; kk < 2; ++kk) {
        bf16x8 kf = *(const bf16x8*)(&Ks[cur][j * 16 + l16][kk * 32 + lq * 8]);
        sf[0][j] = MFMA16(kf, qf[0][kk], sf[0][j]);
        sf[1][j] = MFMA16(kf, qf[1][kk], sf[1][j]);
      }

    // online softmax per subtile (defer-max)
#pragma unroll
    for (int s = 0; s < 2; ++s) {
      float mx = -1e30f;
#pragma unroll
      for (int j = 0; j < 4; ++j)
#pragma unroll
        for (int r = 0; r < 4; ++r) mx = fmaxf(mx, sf[s][j][r]);
      mx = fmaxf(mx, __shfl_xor(mx, 16));
      mx = fmaxf(mx, __shfl_xor(mx, 32));

      if (!__all(mx <= m_run[s] + DEFER_THR)) {
        float mnew = fmaxf(m_run[s], mx);
        float corr = exp2f(m_run[s] - mnew);
        m_run[s] = mnew;
        l_run[s] *= corr;
#pragma unroll
        for (int j = 0; j < 4; ++j) {
          oacc[s][j][0] *= corr; oacc[s][j][1] *= corr;
          oacc[s][j][2] *= corr; oacc[s][j][3] *= corr;
        }
      }

      float rs = 0.f;
#pragma unroll
      for (int j = 0; j < 4; ++j)
#pragma unroll
        for (int r = 0; r < 4; ++r) {
          float pv = exp2f(sf[s][j][r] - m_run[s]);
          sf[s][j][r] = pv;
          rs += pv;
        }
      rs += __shfl_xor(rs, 16);
      rs += __shfl_xor(rs, 32);
      l_run[s] += rs;

#pragma unroll
      for (int j = 0; j < 4; ++j) {
        bf16x4 pk = { (bf16)sf[s][j][0], (bf16)sf[s][j][1], (bf16)sf[s][j][2], (bf16)sf[s][j][3] };
        *(bf16x4*)(&Ps[wave][s][l16][j * 16 + lq * 4]) = pk;
      }
    }
    asm volatile("s_waitcnt lgkmcnt(0)" ::: "memory");

    // PV for both subtiles; vtf read ONCE per (j,kk)
    bf16x8 pf[2][2];
#pragma unroll
    for (int s = 0; s < 2; ++s) {
      pf[s][0] = *(const bf16x8*)(&Ps[wave][s][l16][lq * 8]);
      pf[s][1] = *(const bf16x8*)(&Ps[wave][s][l16][32 + lq * 8]);
    }
#pragma unroll
    for (int j = 0; j < 4; ++j)
#pragma unroll
      for (int kk = 0; kk < 2; ++kk) {
        bf16x8 vtf = *(const bf16x8*)(&Vs[cur][j * 16 + l16][kk * 32 + lq * 8]);
        oacc[0][j] = MFMA16(vtf, pf[0][kk], oacc[0][j]);
        oacc[1][j] = MFMA16(vtf, pf[1][kk], oacc[1][j]);
      }

    if (more) {
      STORE_TILE(cur ^ 1);
      __syncthreads();
    }
  }

#pragma unroll
  for (int s = 0; s < 2; ++s) {
    const float inv = 1.0f / l_run[s];
    const int q = qb * 128 + wave * 32 + s * 16 + l16;
#pragma unroll
    for (int j = 0; j < 4; ++j) {
      size_t off = (size_t)q * HDIM + h * DHEAD + j * 16 + lq * 4;
      float o0 = oacc[s][j][0] * inv, o1 = oacc[s][j][1] * inv,
            o2 = oacc[s][j][2] * inv, o3 = oacc[s][j][3] * inv;
      if (Ob) {
        bf16x4 ov = { (bf16)o0, (bf16)o1, (bf16)o2, (bf16)o3 };
        *(bf16x4*)(Ob + off) = ov;
      }
      if (Of) {
        float4 ov = { o0, o1, o2, o3 };
        *(float4*)(Of + (size_t)p * oStride + off) = ov;
      }
    }
  }
}

// ---------------- mean over P + build concat matrix -------------------------
__global__ void mean_gate_prep_kernel(const float* __restrict__ rc,   // [2][S][H]
                                      const bf16* __restrict__ outb,  // [S][H]
                                      float* __restrict__ rof,        // [S][H]
                                      bf16* __restrict__ acat,        // [S][2H]
                                      int n) {
  int i = blockIdx.x * blockDim.x + threadIdx.x;
  int stride = gridDim.x * blockDim.x;
  for (; i < n; i += stride) {
    float ro = 0.5f * (rc[i] + rc[i + n]);
    rof[i] = ro;
    int srow = i >> 10, col = i & 1023;
    size_t base = (size_t)srow * 2048;
    acat[base + col] = outb[i];
    acat[base + 1024 + col] = (bf16)ro;
  }
}

// ---------------- final gating ----------------------------------------------
__global__ void final_gate_kernel(const float* __restrict__ outf,
                                  const float* __restrict__ rof,
                                  const float* __restrict__ glog,
                                  float* __restrict__ out, int n) {
  int i = blockIdx.x * blockDim.x + threadIdx.x;
  int stride = gridDim.x * blockDim.x;
  for (; i < n; i += stride) {
    float g = 1.0f / (1.0f + __expf(-glog[i]));
    out[i] = outf[i] * (1.0f - g) + rof[i] * g;
  }
}

// ============================================================================
extern "C" void kernel_launch(void* const* d_in, const int* in_sizes, int n_in,
                              void* d_out, int out_size, void* d_ws, size_t ws_size,
                              hipStream_t stream) {
  const float* hs   = (const float*)d_in[0];
  const float* past = (const float*)d_in[1];
  const float* Wq = (const float*)d_in[2];   const float* bq = (const float*)d_in[3];
  const float* Wk = (const float*)d_in[4];   const float* bk = (const float*)d_in[5];
  const float* Wv = (const float*)d_in[6];   const float* bv = (const float*)d_in[7];
  const float* Wo = (const float*)d_in[8];   const float* bo = (const float*)d_in[9];
  const float* Wrq = (const float*)d_in[10]; const float* brq = (const float*)d_in[11];
  const float* Wrk = (const float*)d_in[12]; const float* brk = (const float*)d_in[13];
  const float* Wrv = (const float*)d_in[14]; const float* brv = (const float*)d_in[15];
  const float* Wg  = (const float*)d_in[16]; const float* bg  = (const float*)d_in[17];

  char* wp = (char*)d_ws;
  auto alloc = [&](size_t bytes) -> void* {
    void* p = (void*)wp;
    wp += (bytes + 255) & ~(size_t)255;
    return p;
  };
  const size_t NE = (size_t)S_LEN * HDIM;  // 2M elements

  bf16* hs_b   = (bf16*)alloc(NE * 2);
  bf16* past_b = (bf16*)alloc(2 * NE * 2);
  bf16* Wqt  = (bf16*)alloc((size_t)HDIM * HDIM * 2);
  bf16* Wkt  = (bf16*)alloc((size_t)HDIM * HDIM * 2);
  bf16* Wvt  = (bf16*)alloc((size_t)HDIM * HDIM * 2);
  bf16* Wot  = (bf16*)alloc((size_t)HDIM * HDIM * 2);
  bf16* Wrqt = (bf16*)alloc((size_t)HDIM * HDIM * 2);
  bf16* Wrkt = (bf16*)alloc((size_t)HDIM * HDIM * 2);
  bf16* Wrvt = (bf16*)alloc((size_t)HDIM * HDIM * 2);
  bf16* Wgt  = (bf16*)alloc((size_t)2 * HDIM * HDIM * 2);  // [1024][2048]
  bf16* q_b   = (bf16*)alloc(NE * 2);
  bf16* k_b   = (bf16*)alloc(NE * 2);
  bf16* v_b   = (bf16*)alloc(NE * 2);
  bf16* vT_b  = (bf16*)alloc(NE * 2);
  bf16* ctx_b = (bf16*)alloc(NE * 2);
  bf16* out_b = (bf16*)alloc(NE * 2);
  float* out_f = (float*)alloc(NE * 4);
  bf16* rq_b  = (bf16*)alloc(NE * 2);
  bf16* rk_b  = (bf16*)alloc(2 * NE * 2);
  bf16* rv_b  = (bf16*)alloc(2 * NE * 2);
  bf16* rvT_b = (bf16*)alloc(2 * NE * 2);
  float* rctx_f = (float*)alloc(2 * NE * 4);
  float* ro_f   = (float*)alloc(NE * 4);
  bf16* acat_b  = (bf16*)alloc(2 * NE * 2);
  float* glog_f = (float*)alloc(NE * 4);

  // 1. convert activations to bf16
  cvt_f32_bf16_kernel<<<2048, 256, 0, stream>>>(hs, hs_b, (int)(NE / 4));
  cvt_f32_bf16_kernel<<<2048, 256, 0, stream>>>(past, past_b, (int)(2 * NE / 4));

  // 2. transpose+convert weights (Bt layout [N][K])
  TrArgs ta{};
  ta.j[0] = {Wq, Wqt};  ta.j[1] = {Wk, Wkt};  ta.j[2] = {Wv, Wvt};
  ta.j[3] = {Wo, Wot};  ta.j[4] = {Wrq, Wrqt}; ta.j[5] = {Wrk, Wrkt};
  ta.j[6] = {Wrv, Wrvt};
  transp_cvt_kernel<<<dim3(32, 32, 7), dim3(32, 8), 0, stream>>>(ta, 1024, 1024);
  TrArgs tg{};
  tg.j[0] = {Wg, Wgt};
  transp_cvt_kernel<<<dim3(32, 64, 1), dim3(32, 8), 0, stream>>>(tg, 2048, 1024);

  // 3. big batch: q,k,v + rk(p),rv(p) — 7 jobs, 1792 wgs
  GemmArgs g1{};
  g1.j[0] = {hs_b,        Wqt,  bq,  q_b,        nullptr, QSCALE};
  g1.j[1] = {hs_b,        Wkt,  bk,  k_b,        nullptr, 1.0f};
  g1.j[2] = {hs_b,        Wvt,  bv,  v_b,        nullptr, 1.0f};
  g1.j[3] = {past_b,      Wrkt, brk, rk_b,       nullptr, 1.0f};
  g1.j[4] = {past_b + NE, Wrkt, brk, rk_b + NE,  nullptr, 1.0f};
  g1.j[5] = {past_b,      Wrvt, brv, rv_b,       nullptr, 1.0f};
  g1.j[6] = {past_b + NE, Wrvt, brv, rv_b + NE,  nullptr, 1.0f};
  gemm_bt_kernel<<<dim3(8, 32, 7), 256, 0, stream>>>(g1, 2048, 1024, 1024);

  // 4. per-head transposes: v, rv0, rv1 (batched, z = 3*16)
  ThArgs th{};
  th.j[0] = {v_b, vT_b};
  th.j[1] = {rv_b, rvT_b};
  th.j[2] = {rv_b + NE, rvT_b + NE};
  transp_head_kernel<<<dim3(64, 2, 48), dim3(32, 8), 0, stream>>>(th);

  // 5. self-attention (QBLK=64 kernel: 512 blocks -> 2/CU)
  flash_attn_kernel<<<dim3(32, 16, 1), 256, 0, stream>>>(
      q_b, k_b, vT_b, ctx_b, nullptr, 0, 0, 0);

  // 6. output projection (bf16 + fp32 outputs)
  GemmArgs g2{};
  g2.j[0] = {ctx_b, Wot, bo, out_b, out_f, 1.0f};
  gemm_bt_kernel<<<dim3(8, 32, 1), 256, 0, stream>>>(g2, 2048, 1024, 1024);

  // 7. rq (pre-scaled)
  GemmArgs g3{};
  g3.j[0] = {out_b, Wrqt, brq, rq_b, nullptr, QSCALE};
  gemm_bt_kernel<<<dim3(8, 32, 1), 256, 0, stream>>>(g3, 2048, 1024, 1024);

  // 8. recursive attention (QBLK=128 kernel: 16x16x2 = 512 blocks -> 2/CU)
  flash_attn2_kernel<<<dim3(16, 16, 2), 256, 0, stream>>>(
      rq_b, rk_b, rvT_b, nullptr, rctx_f, NE, NE, NE);

  // 9. mean over P + concat matrix
  mean_gate_prep_kernel<<<2048, 256, 0, stream>>>(rctx_f, out_b, ro_f, acat_b, (int)NE);

  // 10. gate logits: [S][2H] @ Wg
  GemmArgs g4{};
  g4.j[0] = {acat_b, Wgt, bg, nullptr, glog_f, 1.0f};
  gemm_bt_kernel<<<dim3(8, 32, 1), 256, 0, stream>>>(g4, 2048, 1024, 2048);

  // 11. final gated combine -> d_out (fp32)
  final_gate_kernel<<<2048, 256, 0, stream>>>(out_f, ro_f, glog_f, (float*)d_out, (int)NE);
}